// Round 1
// baseline (415.999 us; speedup 1.0000x reference)
//
#include <hip/hip_runtime.h>
#include <hip/hip_bf16.h>

#define NTOK 8192
#define DDIM 1024
#define HDIM 1024
#define NEXP 8

typedef __attribute__((ext_vector_type(8))) short short8;
typedef __attribute__((ext_vector_type(4))) float f32x4;
typedef __attribute__((ext_vector_type(4))) unsigned short us4;

static __device__ __forceinline__ unsigned short f2bf(float f) {
  union { float f; unsigned u; } v; v.f = f;
  return (unsigned short)((v.u + 0x7fffu + ((v.u >> 16) & 1u)) >> 16);
}

static __device__ __forceinline__ void gload16(const void* g, void* l) {
  __builtin_amdgcn_global_load_lds(
      (const __attribute__((address_space(1))) unsigned int*)g,
      (__attribute__((address_space(3))) unsigned int*)l, 16, 0, 0);
}

// ---------------- gate: fp32 logits, top-2, softmax, routing lists; fused x->bf16 ----
__global__ __launch_bounds__(256) void gate_kernel(
    const float* __restrict__ x, const float* __restrict__ Wg,
    const float* __restrict__ bg, unsigned short* __restrict__ xb,
    int* __restrict__ counts, int* __restrict__ tlist, float* __restrict__ wlist)
{
  const int token = blockIdx.x * 4 + (threadIdx.x >> 6);
  const int lane = threadIdx.x & 63;
  const float* xr = x + (size_t)token * DDIM;

  float acc[NEXP];
#pragma unroll
  for (int e = 0; e < NEXP; ++e) acc[e] = 0.f;

#pragma unroll
  for (int q = 0; q < 4; ++q) {
    const int d0 = q * 256 + lane * 4;
    const float4 xv = *(const float4*)(xr + d0);
    us4 hb;
    hb.x = f2bf(xv.x); hb.y = f2bf(xv.y); hb.z = f2bf(xv.z); hb.w = f2bf(xv.w);
    *(us4*)(xb + (size_t)token * DDIM + d0) = hb;
    const float xs[4] = {xv.x, xv.y, xv.z, xv.w};
#pragma unroll
    for (int j = 0; j < 4; ++j) {
      const float* wr = Wg + (size_t)(d0 + j) * NEXP;
      const float4 wa = *(const float4*)wr;
      const float4 wb = *(const float4*)(wr + 4);
      acc[0] += xs[j] * wa.x; acc[1] += xs[j] * wa.y;
      acc[2] += xs[j] * wa.z; acc[3] += xs[j] * wa.w;
      acc[4] += xs[j] * wb.x; acc[5] += xs[j] * wb.y;
      acc[6] += xs[j] * wb.z; acc[7] += xs[j] * wb.w;
    }
  }

#pragma unroll
  for (int e = 0; e < NEXP; ++e) {
#pragma unroll
    for (int off = 32; off >= 1; off >>= 1)
      acc[e] += __shfl_xor(acc[e], off, 64);
  }

  if (lane == 0) {
    float v[NEXP];
#pragma unroll
    for (int e = 0; e < NEXP; ++e) v[e] = acc[e] + bg[e];
    int i0 = 0; float v0 = v[0];
#pragma unroll
    for (int e = 1; e < NEXP; ++e) if (v[e] > v0) { v0 = v[e]; i0 = e; }
    int i1 = -1; float v1 = -3.4e38f;
#pragma unroll
    for (int e = 0; e < NEXP; ++e) if (e != i0 && v[e] > v1) { v1 = v[e]; i1 = e; }
    const float t = __expf(v1 - v0);
    const float w0 = 1.f / (1.f + t);
    const float w1 = t / (1.f + t);
    const int s0 = atomicAdd(&counts[i0], 1);
    tlist[i0 * NTOK + s0] = token; wlist[i0 * NTOK + s0] = w0;
    const int s1 = atomicAdd(&counts[i1], 1);
    tlist[i1 * NTOK + s1] = token; wlist[i1 * NTOK + s1] = w1;
  }
}

// ---------------- We [E][D][H] fp32 -> [E][H][D] bf16 (transpose + convert) ----------
__global__ __launch_bounds__(256) void transpose_we(
    const float* __restrict__ We, unsigned short* __restrict__ wbt)
{
  const int e = blockIdx.z;
  const int h0 = blockIdx.x * 64;
  const int d0 = blockIdx.y * 64;
  __shared__ float t[64][65];
  const int tx = threadIdx.x;
  const int r0 = tx >> 4;
  const int c0 = (tx & 15) * 4;
  const float* src = We + ((size_t)e * DDIM + d0) * HDIM + h0;
#pragma unroll
  for (int i = 0; i < 4; ++i) {
    const int r = r0 + i * 16;
    const float4 v = *(const float4*)(src + (size_t)r * HDIM + c0);
    t[r][c0] = v.x; t[r][c0 + 1] = v.y; t[r][c0 + 2] = v.z; t[r][c0 + 3] = v.w;
  }
  __syncthreads();
#pragma unroll
  for (int i = 0; i < 4; ++i) {
    const int hr = r0 + i * 16;
    us4 o;
    o.x = f2bf(t[c0][hr]);
    o.y = f2bf(t[c0 + 1][hr]);
    o.z = f2bf(t[c0 + 2][hr]);
    o.w = f2bf(t[c0 + 3][hr]);
    *(us4*)(wbt + ((size_t)e * HDIM + h0 + hr) * DDIM + d0 + c0) = o;
  }
}

// ---------------- grouped GEMM: per expert, gathered token rows, bf16 MFMA ----------
__global__ __launch_bounds__(256) void moe_gemm(
    const unsigned short* __restrict__ xb,
    const unsigned short* __restrict__ wbt,
    const float* __restrict__ be,
    const int* __restrict__ counts,
    const int* __restrict__ tlist,
    const float* __restrict__ wlist,
    float* __restrict__ out)
{
  const int e = blockIdx.z;
  const int cnt = counts[e];
  const int tile = blockIdx.y;
  if (tile * 128 >= cnt) return;
  const int n0 = blockIdx.x * 128;

  __shared__ unsigned short As[128 * 64];
  __shared__ unsigned short Bs[128 * 64];

  const int tid = threadIdx.x;
  const int lane = tid & 63;
  const int wv = tid >> 6;
  const int wm = wv >> 1;
  const int wn = wv & 1;

  // staging addressing: row r = q*32 + tid/8, 16B chunk (tid&7); source pre-swizzled
  const int rA = tid >> 3;
  const int kbA = (tid & 7) << 4;
  const unsigned short* aSrc[4];
  const unsigned short* bSrc[4];
  int ldsOff[4];
#pragma unroll
  for (int q = 0; q < 4; ++q) {
    const int r = q * 32 + rA;
    int trow = tile * 128 + r;
    trow = trow < cnt ? trow : cnt - 1;
    const int tok = tlist[e * NTOK + trow];
    const int kbs = kbA ^ ((r & 7) << 4);
    aSrc[q] = xb + (size_t)tok * DDIM + (kbs >> 1);
    bSrc[q] = wbt + ((size_t)e * HDIM + n0 + r) * DDIM + (kbs >> 1);
    ldsOff[q] = r * 64 + (kbA >> 1);
  }

  f32x4 acc[4][4];
#pragma unroll
  for (int m = 0; m < 4; ++m)
#pragma unroll
    for (int n = 0; n < 4; ++n)
      acc[m][n] = (f32x4){0.f, 0.f, 0.f, 0.f};

  for (int kt = 0; kt < DDIM / 64; ++kt) {
    __syncthreads();
#pragma unroll
    for (int q = 0; q < 4; ++q) gload16(aSrc[q] + kt * 64, &As[ldsOff[q]]);
#pragma unroll
    for (int q = 0; q < 4; ++q) gload16(bSrc[q] + kt * 64, &Bs[ldsOff[q]]);
    __syncthreads();

#pragma unroll
    for (int kk = 0; kk < 2; ++kk) {
      const int kb = kk * 64 + ((lane >> 4) << 4);
      short8 af[4], bfr[4];
#pragma unroll
      for (int m = 0; m < 4; ++m) {
        const int r = wm * 64 + m * 16 + (lane & 15);
        af[m] = *(const short8*)((const char*)As + r * 128 + (kb ^ ((r & 7) << 4)));
      }
#pragma unroll
      for (int n = 0; n < 4; ++n) {
        const int r = wn * 64 + n * 16 + (lane & 15);
        bfr[n] = *(const short8*)((const char*)Bs + r * 128 + (kb ^ ((r & 7) << 4)));
      }
#pragma unroll
      for (int m = 0; m < 4; ++m)
#pragma unroll
        for (int n = 0; n < 4; ++n)
          acc[m][n] = __builtin_amdgcn_mfma_f32_16x16x32_bf16(af[m], bfr[n], acc[m][n], 0, 0, 0);
    }
  }

  // epilogue: out[tok][h] += w * (acc + be[e][h])
  const int rbase = wm * 64 + ((lane >> 4) << 2);
  const int cbase = n0 + wn * 64 + (lane & 15);
#pragma unroll
  for (int m = 0; m < 4; ++m) {
#pragma unroll
    for (int r4 = 0; r4 < 4; ++r4) {
      const int trow = tile * 128 + rbase + m * 16 + r4;
      if (trow < cnt) {
        const int tok = tlist[e * NTOK + trow];
        const float w = wlist[e * NTOK + trow];
        float* orow = out + (size_t)tok * HDIM;
#pragma unroll
        for (int n = 0; n < 4; ++n) {
          const int h = cbase + n * 16;
          atomicAdd(orow + h, w * (acc[m][n][r4] + be[e * HDIM + h]));
        }
      }
    }
  }
}

extern "C" void kernel_launch(void* const* d_in, const int* in_sizes, int n_in,
                              void* d_out, int out_size, void* d_ws, size_t ws_size,
                              hipStream_t stream)
{
  const float* x  = (const float*)d_in[0];
  const float* Wg = (const float*)d_in[1];
  const float* bg = (const float*)d_in[2];
  const float* We = (const float*)d_in[3];
  const float* be = (const float*)d_in[4];
  // d_in[5] = k (constant 2 for this problem)

  char* ws = (char*)d_ws;
  int*   counts = (int*)ws;                                   // 256 B
  int*   tlist  = (int*)(ws + 256);                           // 256 KB
  float* wlist  = (float*)(ws + 256 + NEXP * NTOK * 4);       // 256 KB
  unsigned short* xb  = (unsigned short*)(ws + (1 << 20));                      // 16 MB
  unsigned short* wbt = (unsigned short*)(ws + (1 << 20) + (size_t)NTOK * DDIM * 2); // 16 MB
  float* out = (float*)d_out;

  hipMemsetAsync(counts, 0, 256, stream);
  hipMemsetAsync(out, 0, (size_t)out_size * sizeof(float), stream);

  gate_kernel<<<NTOK / 4, 256, 0, stream>>>(x, Wg, bg, xb, counts, tlist, wlist);
  transpose_we<<<dim3(HDIM / 64, DDIM / 64, NEXP), 256, 0, stream>>>(We, wbt);
  moe_gemm<<<dim3(HDIM / 128, NTOK / 128, NEXP), 256, 0, stream>>>(
      xb, wbt, be, counts, tlist, wlist, out);
}

// Round 2
// 258.006 us; speedup vs baseline: 1.6124x; 1.6124x over previous
//
#include <hip/hip_runtime.h>
#include <hip/hip_bf16.h>

#define NTOK 8192
#define DDIM 1024
#define HDIM 1024
#define NEXP 8

typedef __attribute__((ext_vector_type(8))) short short8;
typedef __attribute__((ext_vector_type(4))) float f32x4;
typedef __attribute__((ext_vector_type(4))) unsigned short us4;

static __device__ __forceinline__ unsigned short f2bf(float f) {
  union { float f; unsigned u; } v; v.f = f;
  return (unsigned short)((v.u + 0x7fffu + ((v.u >> 16) & 1u)) >> 16);
}

static __device__ __forceinline__ void gload16(const void* g, void* l) {
  __builtin_amdgcn_global_load_lds(
      (const __attribute__((address_space(1))) unsigned int*)g,
      (__attribute__((address_space(3))) unsigned int*)l, 16, 0, 0);
}

// ---------------- gate: fp32 logits, top-2, softmax; fused x->bf16; NO atomics ------
__global__ __launch_bounds__(256) void gate_kernel(
    const float* __restrict__ x, const float* __restrict__ Wg,
    const float* __restrict__ bg, unsigned short* __restrict__ xb,
    int* __restrict__ sel, float* __restrict__ wts)
{
  const int token = blockIdx.x * 4 + (threadIdx.x >> 6);
  const int lane = threadIdx.x & 63;
  const float* xr = x + (size_t)token * DDIM;

  float acc[NEXP];
#pragma unroll
  for (int e = 0; e < NEXP; ++e) acc[e] = 0.f;

#pragma unroll
  for (int q = 0; q < 4; ++q) {
    const int d0 = q * 256 + lane * 4;
    const float4 xv = *(const float4*)(xr + d0);
    us4 hb;
    hb.x = f2bf(xv.x); hb.y = f2bf(xv.y); hb.z = f2bf(xv.z); hb.w = f2bf(xv.w);
    *(us4*)(xb + (size_t)token * DDIM + d0) = hb;
    const float xs[4] = {xv.x, xv.y, xv.z, xv.w};
#pragma unroll
    for (int j = 0; j < 4; ++j) {
      const float* wr = Wg + (size_t)(d0 + j) * NEXP;
      const float4 wa = *(const float4*)wr;
      const float4 wb = *(const float4*)(wr + 4);
      acc[0] += xs[j] * wa.x; acc[1] += xs[j] * wa.y;
      acc[2] += xs[j] * wa.z; acc[3] += xs[j] * wa.w;
      acc[4] += xs[j] * wb.x; acc[5] += xs[j] * wb.y;
      acc[6] += xs[j] * wb.z; acc[7] += xs[j] * wb.w;
    }
  }

#pragma unroll
  for (int e = 0; e < NEXP; ++e) {
#pragma unroll
    for (int off = 32; off >= 1; off >>= 1)
      acc[e] += __shfl_xor(acc[e], off, 64);
  }

  if (lane == 0) {
    float v[NEXP];
#pragma unroll
    for (int e = 0; e < NEXP; ++e) v[e] = acc[e] + bg[e];
    int i0 = 0; float v0 = v[0];
#pragma unroll
    for (int e = 1; e < NEXP; ++e) if (v[e] > v0) { v0 = v[e]; i0 = e; }
    int i1 = -1; float v1 = -3.4e38f;
#pragma unroll
    for (int e = 0; e < NEXP; ++e) if (e != i0 && v[e] > v1) { v1 = v[e]; i1 = e; }
    const float t = __expf(v1 - v0);
    const float w0 = 1.f / (1.f + t);
    const float w1 = t / (1.f + t);
    sel[token * 2 + 0] = i0;  wts[token * 2 + 0] = w0;
    sel[token * 2 + 1] = i1;  wts[token * 2 + 1] = w1;
  }
}

// ---------------- route: block-aggregated scatter into per-expert lists -------------
__global__ __launch_bounds__(256) void route_kernel(
    const int* __restrict__ sel, const float* __restrict__ wts,
    int* __restrict__ counts, int* __restrict__ tlist, float* __restrict__ wlist)
{
  __shared__ int bin[NEXP];
  __shared__ int base[NEXP];
  const int tid = threadIdx.x;
  if (tid < NEXP) bin[tid] = 0;
  __syncthreads();
  const int idx = blockIdx.x * 256 + tid;          // (token,slot) entry, 16384 total
  const int e = sel[idx];
  const float w = wts[idx];
  const int rank = atomicAdd(&bin[e], 1);          // LDS atomic: within-block rank
  __syncthreads();
  if (tid < NEXP) base[tid] = atomicAdd(&counts[tid], bin[tid]);  // 8 global atomics/block
  __syncthreads();
  const int pos = base[e] + rank;
  tlist[e * NTOK + pos] = idx >> 1;                // token id
  wlist[e * NTOK + pos] = w;
}

// ---------------- We [E][D][H] fp32 -> [E][H][D] bf16 (transpose + convert) ----------
__global__ __launch_bounds__(256) void transpose_we(
    const float* __restrict__ We, unsigned short* __restrict__ wbt)
{
  const int e = blockIdx.z;
  const int h0 = blockIdx.x * 64;
  const int d0 = blockIdx.y * 64;
  __shared__ float t[64][65];
  const int tx = threadIdx.x;
  const int r0 = tx >> 4;
  const int c0 = (tx & 15) * 4;
  const float* src = We + ((size_t)e * DDIM + d0) * HDIM + h0;
#pragma unroll
  for (int i = 0; i < 4; ++i) {
    const int r = r0 + i * 16;
    const float4 v = *(const float4*)(src + (size_t)r * HDIM + c0);
    t[r][c0] = v.x; t[r][c0 + 1] = v.y; t[r][c0 + 2] = v.z; t[r][c0 + 3] = v.w;
  }
  __syncthreads();
#pragma unroll
  for (int i = 0; i < 4; ++i) {
    const int hr = r0 + i * 16;
    us4 o;
    o.x = f2bf(t[c0][hr]);
    o.y = f2bf(t[c0 + 1][hr]);
    o.z = f2bf(t[c0 + 2][hr]);
    o.w = f2bf(t[c0 + 3][hr]);
    *(us4*)(wbt + ((size_t)e * HDIM + h0 + hr) * DDIM + d0 + c0) = o;
  }
}

// ---------------- grouped GEMM: per expert, gathered token rows, bf16 MFMA ----------
__global__ __launch_bounds__(256) void moe_gemm(
    const unsigned short* __restrict__ xb,
    const unsigned short* __restrict__ wbt,
    const float* __restrict__ be,
    const int* __restrict__ counts,
    const int* __restrict__ tlist,
    const float* __restrict__ wlist,
    float* __restrict__ out)
{
  const int e = blockIdx.z;
  const int cnt = counts[e];
  const int tile = blockIdx.y;
  if (tile * 128 >= cnt) return;
  const int n0 = blockIdx.x * 128;

  __shared__ unsigned short As[128 * 64];
  __shared__ unsigned short Bs[128 * 64];

  const int tid = threadIdx.x;
  const int lane = tid & 63;
  const int wv = tid >> 6;
  const int wm = wv >> 1;
  const int wn = wv & 1;

  // staging addressing: row r = q*32 + tid/8, 16B chunk (tid&7); source pre-swizzled
  const int rA = tid >> 3;
  const int kbA = (tid & 7) << 4;
  const unsigned short* aSrc[4];
  const unsigned short* bSrc[4];
  int ldsOff[4];
#pragma unroll
  for (int q = 0; q < 4; ++q) {
    const int r = q * 32 + rA;
    int trow = tile * 128 + r;
    trow = trow < cnt ? trow : cnt - 1;
    const int tok = tlist[e * NTOK + trow];
    const int kbs = kbA ^ ((r & 7) << 4);
    aSrc[q] = xb + (size_t)tok * DDIM + (kbs >> 1);
    bSrc[q] = wbt + ((size_t)e * HDIM + n0 + r) * DDIM + (kbs >> 1);
    ldsOff[q] = r * 64 + (kbA >> 1);
  }

  f32x4 acc[4][4];
#pragma unroll
  for (int m = 0; m < 4; ++m)
#pragma unroll
    for (int n = 0; n < 4; ++n)
      acc[m][n] = (f32x4){0.f, 0.f, 0.f, 0.f};

  for (int kt = 0; kt < DDIM / 64; ++kt) {
    __syncthreads();
#pragma unroll
    for (int q = 0; q < 4; ++q) gload16(aSrc[q] + kt * 64, &As[ldsOff[q]]);
#pragma unroll
    for (int q = 0; q < 4; ++q) gload16(bSrc[q] + kt * 64, &Bs[ldsOff[q]]);
    __syncthreads();

#pragma unroll
    for (int kk = 0; kk < 2; ++kk) {
      const int kb = kk * 64 + ((lane >> 4) << 4);
      short8 af[4], bfr[4];
#pragma unroll
      for (int m = 0; m < 4; ++m) {
        const int r = wm * 64 + m * 16 + (lane & 15);
        af[m] = *(const short8*)((const char*)As + r * 128 + (kb ^ ((r & 7) << 4)));
      }
#pragma unroll
      for (int n = 0; n < 4; ++n) {
        const int r = wn * 64 + n * 16 + (lane & 15);
        bfr[n] = *(const short8*)((const char*)Bs + r * 128 + (kb ^ ((r & 7) << 4)));
      }
#pragma unroll
      for (int m = 0; m < 4; ++m)
#pragma unroll
        for (int n = 0; n < 4; ++n)
          acc[m][n] = __builtin_amdgcn_mfma_f32_16x16x32_bf16(af[m], bfr[n], acc[m][n], 0, 0, 0);
    }
  }

  // epilogue: out[tok][h] += w * (acc + be[e][h])
  const int rbase = wm * 64 + ((lane >> 4) << 2);
  const int cbase = n0 + wn * 64 + (lane & 15);
#pragma unroll
  for (int m = 0; m < 4; ++m) {
#pragma unroll
    for (int r4 = 0; r4 < 4; ++r4) {
      const int trow = tile * 128 + rbase + m * 16 + r4;
      if (trow < cnt) {
        const int tok = tlist[e * NTOK + trow];
        const float w = wlist[e * NTOK + trow];
        float* orow = out + (size_t)tok * HDIM;
#pragma unroll
        for (int n = 0; n < 4; ++n) {
          const int h = cbase + n * 16;
          atomicAdd(orow + h, w * (acc[m][n][r4] + be[e * HDIM + h]));
        }
      }
    }
  }
}

extern "C" void kernel_launch(void* const* d_in, const int* in_sizes, int n_in,
                              void* d_out, int out_size, void* d_ws, size_t ws_size,
                              hipStream_t stream)
{
  const float* x  = (const float*)d_in[0];
  const float* Wg = (const float*)d_in[1];
  const float* bg = (const float*)d_in[2];
  const float* We = (const float*)d_in[3];
  const float* be = (const float*)d_in[4];
  // d_in[5] = k (constant 2 for this problem)

  char* ws = (char*)d_ws;
  int*   counts = (int*)ws;                                   // 256 B
  int*   tlist  = (int*)(ws + 256);                           // 256 KB
  float* wlist  = (float*)(ws + 256 + NEXP * NTOK * 4);       // 256 KB
  int*   sel    = (int*)(ws + 256 + 2 * NEXP * NTOK * 4);     // 64 KB
  float* wts    = (float*)(ws + 256 + 2 * NEXP * NTOK * 4 + 2 * NTOK * 4); // 64 KB
  unsigned short* xb  = (unsigned short*)(ws + (1 << 20));                      // 16 MB
  unsigned short* wbt = (unsigned short*)(ws + (1 << 20) + (size_t)NTOK * DDIM * 2); // 16 MB
  float* out = (float*)d_out;

  hipMemsetAsync(counts, 0, 256, stream);
  hipMemsetAsync(out, 0, (size_t)out_size * sizeof(float), stream);

  gate_kernel<<<NTOK / 4, 256, 0, stream>>>(x, Wg, bg, xb, sel, wts);
  route_kernel<<<2 * NTOK / 256, 256, 0, stream>>>(sel, wts, counts, tlist, wlist);
  transpose_we<<<dim3(HDIM / 64, DDIM / 64, NEXP), 256, 0, stream>>>(We, wbt);
  moe_gemm<<<dim3(HDIM / 128, NTOK / 128, NEXP), 256, 0, stream>>>(
      xb, wbt, be, counts, tlist, wlist, out);
}

// Round 3
// 219.467 us; speedup vs baseline: 1.8955x; 1.1756x over previous
//
#include <hip/hip_runtime.h>
#include <hip/hip_bf16.h>
#include <hip/hip_fp16.h>

#define NTOK 8192
#define DDIM 1024
#define HDIM 1024
#define NEXP 8

typedef __attribute__((ext_vector_type(8))) short short8;
typedef __attribute__((ext_vector_type(4))) float f32x4;
typedef __attribute__((ext_vector_type(4))) unsigned short us4;

static __device__ __forceinline__ unsigned short f2bf(float f) {
  union { float f; unsigned u; } v; v.f = f;
  return (unsigned short)((v.u + 0x7fffu + ((v.u >> 16) & 1u)) >> 16);
}

static __device__ __forceinline__ void gload16(const void* g, void* l) {
  __builtin_amdgcn_global_load_lds(
      (const __attribute__((address_space(1))) unsigned int*)g,
      (__attribute__((address_space(3))) unsigned int*)l, 16, 0, 0);
}

// ---------------- gate: fp32 logits, top-2, softmax; fused x->bf16; NO atomics ------
__global__ __launch_bounds__(256) void gate_kernel(
    const float* __restrict__ x, const float* __restrict__ Wg,
    const float* __restrict__ bg, unsigned short* __restrict__ xb,
    int* __restrict__ sel, float* __restrict__ wts)
{
  const int token = blockIdx.x * 4 + (threadIdx.x >> 6);
  const int lane = threadIdx.x & 63;
  const float* xr = x + (size_t)token * DDIM;

  float acc[NEXP];
#pragma unroll
  for (int e = 0; e < NEXP; ++e) acc[e] = 0.f;

#pragma unroll
  for (int q = 0; q < 4; ++q) {
    const int d0 = q * 256 + lane * 4;
    const float4 xv = *(const float4*)(xr + d0);
    us4 hb;
    hb.x = f2bf(xv.x); hb.y = f2bf(xv.y); hb.z = f2bf(xv.z); hb.w = f2bf(xv.w);
    *(us4*)(xb + (size_t)token * DDIM + d0) = hb;
    const float xs[4] = {xv.x, xv.y, xv.z, xv.w};
#pragma unroll
    for (int j = 0; j < 4; ++j) {
      const float* wr = Wg + (size_t)(d0 + j) * NEXP;
      const float4 wa = *(const float4*)wr;
      const float4 wb = *(const float4*)(wr + 4);
      acc[0] += xs[j] * wa.x; acc[1] += xs[j] * wa.y;
      acc[2] += xs[j] * wa.z; acc[3] += xs[j] * wa.w;
      acc[4] += xs[j] * wb.x; acc[5] += xs[j] * wb.y;
      acc[6] += xs[j] * wb.z; acc[7] += xs[j] * wb.w;
    }
  }

#pragma unroll
  for (int e = 0; e < NEXP; ++e) {
#pragma unroll
    for (int off = 32; off >= 1; off >>= 1)
      acc[e] += __shfl_xor(acc[e], off, 64);
  }

  if (lane == 0) {
    float v[NEXP];
#pragma unroll
    for (int e = 0; e < NEXP; ++e) v[e] = acc[e] + bg[e];
    int i0 = 0; float v0 = v[0];
#pragma unroll
    for (int e = 1; e < NEXP; ++e) if (v[e] > v0) { v0 = v[e]; i0 = e; }
    int i1 = -1; float v1 = -3.4e38f;
#pragma unroll
    for (int e = 0; e < NEXP; ++e) if (e != i0 && v[e] > v1) { v1 = v[e]; i1 = e; }
    const float t = __expf(v1 - v0);
    const float w0 = 1.f / (1.f + t);
    const float w1 = t / (1.f + t);
    sel[token * 2 + 0] = i0;  wts[token * 2 + 0] = w0;
    sel[token * 2 + 1] = i1;  wts[token * 2 + 1] = w1;
  }
}

// ---------------- route: block-aggregated scatter into per-expert lists -------------
__global__ __launch_bounds__(256) void route_kernel(
    const int* __restrict__ sel, const float* __restrict__ wts,
    int* __restrict__ counts, int* __restrict__ tlist, float* __restrict__ wlist,
    int* __restrict__ dstrow)
{
  __shared__ int bin[NEXP];
  __shared__ int base[NEXP];
  const int tid = threadIdx.x;
  if (tid < NEXP) bin[tid] = 0;
  __syncthreads();
  const int idx = blockIdx.x * 256 + tid;          // (token,slot) entry, 16384 total
  const int e = sel[idx];
  const float w = wts[idx];
  const int rank = atomicAdd(&bin[e], 1);          // LDS atomic: within-block rank
  __syncthreads();
  if (tid < NEXP) base[tid] = atomicAdd(&counts[tid], bin[tid]);  // 8 global atomics/block
  __syncthreads();
  const int pos = base[e] + rank;
  tlist[e * NTOK + pos] = idx >> 1;                // token id
  wlist[e * NTOK + pos] = w;
  dstrow[e * NTOK + pos] = idx;                    // partial-output row = token*2+slot
}

// ---------------- We [E][D][H] fp32 -> [E][H][D] bf16 (transpose + convert) ----------
__global__ __launch_bounds__(256) void transpose_we(
    const float* __restrict__ We, unsigned short* __restrict__ wbt)
{
  const int e = blockIdx.z;
  const int h0 = blockIdx.x * 64;
  const int d0 = blockIdx.y * 64;
  __shared__ float t[64][65];
  const int tx = threadIdx.x;
  const int r0 = tx >> 4;
  const int c0 = (tx & 15) * 4;
  const float* src = We + ((size_t)e * DDIM + d0) * HDIM + h0;
#pragma unroll
  for (int i = 0; i < 4; ++i) {
    const int r = r0 + i * 16;
    const float4 v = *(const float4*)(src + (size_t)r * HDIM + c0);
    t[r][c0] = v.x; t[r][c0 + 1] = v.y; t[r][c0 + 2] = v.z; t[r][c0 + 3] = v.w;
  }
  __syncthreads();
#pragma unroll
  for (int i = 0; i < 4; ++i) {
    const int hr = r0 + i * 16;
    us4 o;
    o.x = f2bf(t[c0][hr]);
    o.y = f2bf(t[c0 + 1][hr]);
    o.z = f2bf(t[c0 + 2][hr]);
    o.w = f2bf(t[c0 + 3][hr]);
    *(us4*)(wbt + ((size_t)e * HDIM + h0 + hr) * DDIM + d0 + c0) = o;
  }
}

// ------- grouped GEMM: 256x128 tile, 8 waves, gathered rows, fp16 partial stores ----
__global__ __launch_bounds__(512, 4) void moe_gemm(
    const unsigned short* __restrict__ xb,
    const unsigned short* __restrict__ wbt,
    const float* __restrict__ be,
    const int* __restrict__ counts,
    const int* __restrict__ tlist,
    const float* __restrict__ wlist,
    const int* __restrict__ dstrow,
    __half* __restrict__ yb)
{
  const int e = blockIdx.z;
  const int cnt = counts[e];
  const int tile = blockIdx.y;
  if (tile * 256 >= cnt) return;
  const int n0 = blockIdx.x * 128;

  __shared__ unsigned short As[256 * 64];   // 32 KB
  __shared__ unsigned short Bs[128 * 64];   // 16 KB

  const int tid = threadIdx.x;              // 0..511
  const int lane = tid & 63;
  const int wv = tid >> 6;                  // 0..7
  const int wm = wv >> 1;                   // 0..3  (m position)
  const int wn = wv & 1;                    // 0..1  (n position)

  // staging: row r, 16B chunk (tid&7); swizzled SOURCE + linear LDS dest (rule 21)
  const int rA = tid >> 3;                  // 0..63
  const int kbA = (tid & 7) << 4;           // byte chunk in 128B row
  int aOff[4]; int bOff[2]; int ldsA[4]; int ldsB[2];
#pragma unroll
  for (int q = 0; q < 4; ++q) {
    const int r = q * 64 + rA;              // 0..255
    int trow = tile * 256 + r;
    trow = trow < cnt ? trow : cnt - 1;
    const int tok = tlist[e * NTOK + trow];
    const int kbs = kbA ^ ((r & 7) << 4);
    aOff[q] = tok * DDIM + (kbs >> 1);
    ldsA[q] = r * 64 + (kbA >> 1);
  }
#pragma unroll
  for (int q = 0; q < 2; ++q) {
    const int r = q * 64 + rA;              // 0..127
    const int kbs = kbA ^ ((r & 7) << 4);
    bOff[q] = (e * HDIM + n0 + r) * DDIM + (kbs >> 1);
    ldsB[q] = r * 64 + (kbA >> 1);
  }

  f32x4 acc[4][4];
#pragma unroll
  for (int m = 0; m < 4; ++m)
#pragma unroll
    for (int n = 0; n < 4; ++n)
      acc[m][n] = (f32x4){0.f, 0.f, 0.f, 0.f};

  for (int kt = 0; kt < DDIM / 64; ++kt) {
    __syncthreads();
#pragma unroll
    for (int q = 0; q < 4; ++q) gload16(xb + aOff[q] + kt * 64, &As[ldsA[q]]);
#pragma unroll
    for (int q = 0; q < 2; ++q) gload16(wbt + bOff[q] + kt * 64, &Bs[ldsB[q]]);
    __syncthreads();

#pragma unroll
    for (int kk = 0; kk < 2; ++kk) {
      const int kb = kk * 64 + ((lane >> 4) << 4);
      short8 af[4], bfr[4];
#pragma unroll
      for (int m = 0; m < 4; ++m) {
        const int r = wm * 64 + m * 16 + (lane & 15);
        af[m] = *(const short8*)((const char*)As + r * 128 + (kb ^ ((r & 7) << 4)));
      }
#pragma unroll
      for (int n = 0; n < 4; ++n) {
        const int r = wn * 64 + n * 16 + (lane & 15);
        bfr[n] = *(const short8*)((const char*)Bs + r * 128 + (kb ^ ((r & 7) << 4)));
      }
#pragma unroll
      for (int m = 0; m < 4; ++m)
#pragma unroll
        for (int n = 0; n < 4; ++n)
          acc[m][n] = __builtin_amdgcn_mfma_f32_16x16x32_bf16(af[m], bfr[n], acc[m][n], 0, 0, 0);
    }
  }

  // epilogue: yb[dstrow][h] = w * (acc + be[e][h])  (plain fp16 stores, no atomics)
  const int rbase = wm * 64 + ((lane >> 4) << 2);
  const int cb = lane & 15;
  float bev[4];
#pragma unroll
  for (int n = 0; n < 4; ++n) bev[n] = be[e * HDIM + n0 + wn * 64 + n * 16 + cb];
#pragma unroll
  for (int m = 0; m < 4; ++m) {
#pragma unroll
    for (int r4 = 0; r4 < 4; ++r4) {
      const int trow = tile * 256 + rbase + m * 16 + r4;
      if (trow < cnt) {
        const int drow = dstrow[e * NTOK + trow];
        const float w = wlist[e * NTOK + trow];
        __half* yrow = yb + (size_t)drow * HDIM + n0 + wn * 64 + cb;
#pragma unroll
        for (int n = 0; n < 4; ++n)
          yrow[n * 16] = __float2half(w * (acc[m][n][r4] + bev[n]));
      }
    }
  }
}

// ---------------- combine: out[tok] = partial[tok*2] + partial[tok*2+1] -------------
__global__ __launch_bounds__(256) void combine_kernel(
    const __half* __restrict__ yb, float* __restrict__ out)
{
  const int g = blockIdx.x * 256 + threadIdx.x;   // one per 8 outputs
  const int tok = g >> 7;
  const int h0 = (g & 127) * 8;
  const short8 p0 = *(const short8*)(yb + ((size_t)tok * 2) * HDIM + h0);
  const short8 p1 = *(const short8*)(yb + ((size_t)tok * 2 + 1) * HDIM + h0);
  float r[8];
#pragma unroll
  for (int j = 0; j < 8; ++j) {
    __half a = *(const __half*)&((const short*)&p0)[j];
    __half b = *(const __half*)&((const short*)&p1)[j];
    r[j] = __half2float(a) + __half2float(b);
  }
  float* o = out + (size_t)tok * HDIM + h0;
  *(float4*)o = (float4){r[0], r[1], r[2], r[3]};
  *(float4*)(o + 4) = (float4){r[4], r[5], r[6], r[7]};
}

extern "C" void kernel_launch(void* const* d_in, const int* in_sizes, int n_in,
                              void* d_out, int out_size, void* d_ws, size_t ws_size,
                              hipStream_t stream)
{
  const float* x  = (const float*)d_in[0];
  const float* Wg = (const float*)d_in[1];
  const float* bg = (const float*)d_in[2];
  const float* We = (const float*)d_in[3];
  const float* be = (const float*)d_in[4];
  // d_in[5] = k (constant 2 for this problem)

  char* ws = (char*)d_ws;
  int*   counts = (int*)ws;                                   // 256 B
  int*   tlist  = (int*)(ws + 256);                           // 256 KB
  float* wlist  = (float*)(ws + 256 + NEXP * NTOK * 4);       // 256 KB
  int*   dstrow = (int*)(ws + 256 + 2 * NEXP * NTOK * 4);     // 256 KB
  int*   sel    = (int*)(ws + 256 + 3 * NEXP * NTOK * 4);     // 64 KB
  float* wts    = (float*)(ws + 256 + 3 * NEXP * NTOK * 4 + 2 * NTOK * 4); // 64 KB
  unsigned short* xb  = (unsigned short*)(ws + (1 << 21));                           // 16 MB
  unsigned short* wbt = (unsigned short*)(ws + (1 << 21) + (size_t)NTOK * DDIM * 2); // 16 MB
  __half* yb = (__half*)(ws + (1 << 21) + 2 * (size_t)NTOK * DDIM * 2);              // 32 MB
  float* out = (float*)d_out;

  hipMemsetAsync(counts, 0, 256, stream);

  gate_kernel<<<NTOK / 4, 256, 0, stream>>>(x, Wg, bg, xb, sel, wts);
  route_kernel<<<2 * NTOK / 256, 256, 0, stream>>>(sel, wts, counts, tlist, wlist, dstrow);
  transpose_we<<<dim3(HDIM / 64, DDIM / 64, NEXP), 256, 0, stream>>>(We, wbt);
  moe_gemm<<<dim3(HDIM / 128, NTOK / 256, NEXP), 512, 0, stream>>>(
      xb, wbt, be, counts, tlist, wlist, dstrow, yb);
  combine_kernel<<<NTOK * HDIM / 8 / 256, 256, 0, stream>>>(yb, out);
}